// Round 5
// baseline (340.178 us; speedup 1.0000x reference)
//
#include <hip/hip_runtime.h>

typedef __attribute__((ext_vector_type(8))) short short8;
typedef __attribute__((ext_vector_type(4))) float f32x4;

#define NSTEPS 16

__device__ __forceinline__ unsigned short bf16rne(float f) {
  unsigned int u = __float_as_uint(f);
  u += 0x7FFFu + ((u >> 16) & 1u);
  return (unsigned short)(u >> 16);
}

#if __has_builtin(__builtin_amdgcn_cvt_pk_bf16_f32)
typedef __attribute__((ext_vector_type(2))) __bf16 v2bf16;
__device__ __forceinline__ unsigned int pk2(float a, float b) {
  v2bf16 t = __builtin_amdgcn_cvt_pk_bf16_f32(a, b);
  unsigned int r;
  __builtin_memcpy(&r, &t, 4);
  return r;
}
#else
__device__ __forceinline__ unsigned int pk2(float a, float b) {
  unsigned int ua = __float_as_uint(a), ub = __float_as_uint(b);
  ua += 0x7FFFu + ((ua >> 16) & 1u);
  ub += 0x7FFFu + ((ub >> 16) & 1u);
  return (ua >> 16) | (ub & 0xFFFF0000u);
}
#endif

__device__ __forceinline__ float tanh_fast(float x) {
  // tanh(x) = 1 - 2/(e^{2x}+1); e->inf => 1, e->0 => -1 (no clamp needed)
  float e = __builtin_amdgcn_exp2f(x * 2.8853900817779268f);
  return __builtin_fmaf(-2.0f, __builtin_amdgcn_rcpf(e + 1.0f), 1.0f);
}

// Pre-shuffle fp32 weights -> bf16 MFMA fragments (B-frag of W == A-frag of W^T).
// lane holds W[k = 32*ks + 8*(lane>>4) + j][c = 16*t + (lane&15)], j=0..7
__global__ void ffjord_setup(const float* __restrict__ W1a, const float* __restrict__ W2a,
                             const float* __restrict__ W3a, const float* __restrict__ W1b,
                             const float* __restrict__ W2b, const float* __restrict__ W3b,
                             unsigned short* __restrict__ ws) {
  int gid = blockIdx.x * blockDim.x + threadIdx.x;   // 0..24575
  int bij = gid / 12288;
  int r = gid - bij * 12288;
  const float* W1 = bij ? W1b : W1a;
  const float* W2 = bij ? W2b : W2a;
  const float* W3 = bij ? W3b : W3a;
  unsigned short* o = ws + bij * 98304;
  const float* src;
  int kstride;
  if (r < 2048) {                 // W1f
    int lane = r & 63, nt = (r >> 6) & 15, ks = r >> 10;
    int k0 = ks * 32 + (lane >> 4) * 8, n = nt * 16 + (lane & 15);
    src = W1 + k0 * 256 + n; kstride = 256; o += r * 8;
  } else if (r < 10240) {         // W2f
    int rr = r - 2048;
    int lane = rr & 63, nt = (rr >> 6) & 15, ks = rr >> 10;
    int k0 = ks * 32 + (lane >> 4) * 8, n = nt * 16 + (lane & 15);
    src = W2 + k0 * 256 + n; kstride = 256; o += 16384 + rr * 8;
  } else {                        // W3f
    int rr = r - 10240;
    int lane = rr & 63, nt = (rr >> 6) & 3, ks = rr >> 8;
    int k0 = ks * 32 + (lane >> 4) * 8, n = nt * 16 + (lane & 15);
    src = W3 + k0 * 64 + n; kstride = 64; o += 81920 + rr * 8;
  }
  #pragma unroll
  for (int j = 0; j < 8; j++) o[j] = bf16rne(src[j * kstride]);
}

// 1024 threads / 16 waves per block, 16 batch rows. Wave w owns m-tile w of
// layers 1/2 (weights register-resident); L3 = 4 m-tiles x 2 K-halves on waves
// 0-7 (2 fp32 partial buffers). State: 1 element/thread (row = wave, dim = lane).
__global__ __launch_bounds__(1024, 4) void ffjord_main(
    const float* __restrict__ x, float* __restrict__ out,
    const unsigned short* __restrict__ ws,
    const float* __restrict__ W1a, const float* __restrict__ b1a,
    const float* __restrict__ b2a, const float* __restrict__ b3a,
    const float* __restrict__ W1b, const float* __restrict__ b1b,
    const float* __restrict__ b2b, const float* __restrict__ b3b) {
  // zA: [ks2][q4] groups of (16 rows x 8 j) ushorts, each group padded 256B->272B
  __shared__ __align__(16) unsigned short zA[1088];
  __shared__ __align__(16) unsigned short h1A[4096];   // [ks8][q4][row16][j8]
  __shared__ __align__(16) unsigned short h2A[4096];
  __shared__ __align__(16) float fbuf[2][16 * 68];     // L3 K-half partials

  const int tid = threadIdx.x;
  const int wave = tid >> 6;        // 0..15
  const int lane = tid & 63;
  const int cl = lane & 15;
  const int qd = lane >> 4;
  const int mt3 = wave & 3;         // L3 m-tile (waves 0-7)
  const int kh = wave >> 2;         // L3 K-half (0/1 valid for waves 0-7)
  const int c3 = mt3 * 16 + qd * 4; // L3 output base dim
  const int row0 = blockIdx.x * 16;
  const int row = wave;             // batch row owned for state
  const int d0 = lane;              // state dim owned

  // z write offset (ushort units, padded groups)
  const int zoff = ((d0 >> 5) * 4 + ((d0 >> 3) & 3)) * 136 + row * 8 + (d0 & 7);
  // zB-frag read base for this lane (ks via +544 ushorts)
  const int zrb = qd * 136 + cl * 8;
  // L1/L2 output tile: wave w owns hidden dims [w*16, w*16+16)
  const int c0 = wave * 16 + qd * 4;
  const int hoff = (c0 >> 5) * 512 + ((c0 & 31) >> 3) * 128 + cl * 8 + (c0 & 7);

  const float hstep = 1.0f / 16.0f;

  float y = x[(row0 + row) * 64 + d0];
  float k[6];

  const float ACO[6][5] = {
      {0.f, 0.f, 0.f, 0.f, 0.f},
      {1.f / 5.f, 0.f, 0.f, 0.f, 0.f},
      {3.f / 40.f, 9.f / 40.f, 0.f, 0.f, 0.f},
      {44.f / 45.f, -56.f / 15.f, 32.f / 9.f, 0.f, 0.f},
      {19372.f / 6561.f, -25360.f / 2187.f, 64448.f / 6561.f, -212.f / 729.f, 0.f},
      {9017.f / 3168.f, -355.f / 33.f, 46732.f / 5247.f, 49.f / 176.f, -5103.f / 18656.f}};
  const float CT[6] = {0.0f, 0.2f, 0.3f, 0.8f, 8.0f / 9.0f, 1.0f};
  const float BW0 = 35.f / 384.f, BW2 = 500.f / 1113.f, BW3 = 125.f / 192.f,
              BW4 = -2187.f / 6784.f, BW5 = 11.f / 84.f;

  for (int bij = 0; bij < 2; bij++) {
    const unsigned short* wsb = ws + bij * 98304;
    const float* W1 = bij ? W1b : W1a;
    const float* b1 = bij ? b1b : b1a;
    const float* b2 = bij ? b2b : b2a;
    const float* b3 = bij ? b3b : b3a;

    // per-thread bias/t-row vectors for this wave's hidden slots
    f32x4 b1c = *(const f32x4*)(b1 + c0);
    f32x4 w1t4 = *(const f32x4*)(W1 + 64 * 256 + c0);
    f32x4 b2c = *(const f32x4*)(b2 + c0);
    f32x4 b3c;
    if (kh == 0) b3c = *(const f32x4*)(b3 + c3);
    else { b3c[0] = 0.f; b3c[1] = 0.f; b3c[2] = 0.f; b3c[3] = 0.f; }

    // register-resident weight fragments (A-operand of W^T)
    const short8* w1p = (const short8*)wsb;
    const short8* w2p = (const short8*)(wsb + 16384);
    const short8* w3p = (const short8*)(wsb + 81920);
    short8 w1f[2];
    #pragma unroll
    for (int ks = 0; ks < 2; ks++)
      w1f[ks] = w1p[(ks * 16 + wave) * 64 + lane];
    short8 w2f[8];
    #pragma unroll
    for (int ks = 0; ks < 8; ks++)
      w2f[ks] = w2p[(ks * 16 + wave) * 64 + lane];
    short8 w3f[4];
    if (wave < 8) {
      #pragma unroll
      for (int kk = 0; kk < 4; kk++)
        w3f[kk] = w3p[((kh * 4 + kk) * 4 + mt3) * 64 + lane];
    }

    for (int step = 0; step < NSTEPS; step++) {
      float stepf = (float)step;
      #pragma unroll
      for (int s = 0; s < 6; s++) {
        float ts = (stepf + CT[s]) * hstep;

        // ---- phase 1: z = y + h*sum(a_sj * k_j) -> bf16 -> one b16 LDS write
        {
          float z = y;
          #pragma unroll
          for (int j = 0; j < 5; j++)
            if (j < s) z += (hstep * ACO[s][j]) * k[j];
          zA[zoff] = bf16rne(z);
        }
        __syncthreads();

        // ---- layer 1: h1 = tanh(W1^T z + b1 + t*W1t), K=64, one m-tile/wave
        {
          short8 a0 = *(const short8*)(zA + zrb);
          short8 a1 = *(const short8*)(zA + zrb + 544);
          f32x4 acc;
          #pragma unroll
          for (int r = 0; r < 4; r++)
            acc[r] = __builtin_fmaf(ts, w1t4[r], b1c[r]);
          acc = __builtin_amdgcn_mfma_f32_16x16x32_bf16(w1f[0], a0, acc, 0, 0, 0);
          acc = __builtin_amdgcn_mfma_f32_16x16x32_bf16(w1f[1], a1, acc, 0, 0, 0);
          uint2 pv;
          pv.x = pk2(tanh_fast(acc[0]), tanh_fast(acc[1]));
          pv.y = pk2(tanh_fast(acc[2]), tanh_fast(acc[3]));
          *(uint2*)(h1A + hoff) = pv;
        }
        __syncthreads();

        // ---- layer 2: h2 = tanh(W2^T h1 + b2), K=256
        // preload all 8 fragments, then 4 independent accumulator chains
        {
          short8 hb[8];
          #pragma unroll
          for (int ks = 0; ks < 8; ks++)
            hb[ks] = ((const short8*)h1A)[ks * 64 + lane];
          f32x4 accP = b2c;
          f32x4 accQ; accQ[0] = 0.f; accQ[1] = 0.f; accQ[2] = 0.f; accQ[3] = 0.f;
          f32x4 accR = accQ, accS = accQ;
          accP = __builtin_amdgcn_mfma_f32_16x16x32_bf16(w2f[0], hb[0], accP, 0, 0, 0);
          accQ = __builtin_amdgcn_mfma_f32_16x16x32_bf16(w2f[1], hb[1], accQ, 0, 0, 0);
          accR = __builtin_amdgcn_mfma_f32_16x16x32_bf16(w2f[2], hb[2], accR, 0, 0, 0);
          accS = __builtin_amdgcn_mfma_f32_16x16x32_bf16(w2f[3], hb[3], accS, 0, 0, 0);
          accP = __builtin_amdgcn_mfma_f32_16x16x32_bf16(w2f[4], hb[4], accP, 0, 0, 0);
          accQ = __builtin_amdgcn_mfma_f32_16x16x32_bf16(w2f[5], hb[5], accQ, 0, 0, 0);
          accR = __builtin_amdgcn_mfma_f32_16x16x32_bf16(w2f[6], hb[6], accR, 0, 0, 0);
          accS = __builtin_amdgcn_mfma_f32_16x16x32_bf16(w2f[7], hb[7], accS, 0, 0, 0);
          uint2 pv;
          float v0 = (accP[0] + accR[0]) + (accQ[0] + accS[0]);
          float v1 = (accP[1] + accR[1]) + (accQ[1] + accS[1]);
          float v2 = (accP[2] + accR[2]) + (accQ[2] + accS[2]);
          float v3 = (accP[3] + accR[3]) + (accQ[3] + accS[3]);
          pv.x = pk2(tanh_fast(v0), tanh_fast(v1));
          pv.y = pk2(tanh_fast(v2), tanh_fast(v3));
          *(uint2*)(h2A + hoff) = pv;
        }
        __syncthreads();

        // ---- layer 3: f = W3^T h2 + b3, K-half per wave (waves 0-7 only)
        if (wave < 8) {
          short8 hb0 = ((const short8*)h2A)[(kh * 4 + 0) * 64 + lane];
          short8 hb1 = ((const short8*)h2A)[(kh * 4 + 1) * 64 + lane];
          short8 hb2 = ((const short8*)h2A)[(kh * 4 + 2) * 64 + lane];
          short8 hb3 = ((const short8*)h2A)[(kh * 4 + 3) * 64 + lane];
          f32x4 accP = b3c;
          f32x4 accQ; accQ[0] = 0.f; accQ[1] = 0.f; accQ[2] = 0.f; accQ[3] = 0.f;
          accP = __builtin_amdgcn_mfma_f32_16x16x32_bf16(w3f[0], hb0, accP, 0, 0, 0);
          accQ = __builtin_amdgcn_mfma_f32_16x16x32_bf16(w3f[1], hb1, accQ, 0, 0, 0);
          accP = __builtin_amdgcn_mfma_f32_16x16x32_bf16(w3f[2], hb2, accP, 0, 0, 0);
          accQ = __builtin_amdgcn_mfma_f32_16x16x32_bf16(w3f[3], hb3, accQ, 0, 0, 0);
          f32x4 res;
          #pragma unroll
          for (int r = 0; r < 4; r++) res[r] = accP[r] + accQ[r];
          *(f32x4*)(&fbuf[kh][cl * 68 + c3]) = res;
        }
        __syncthreads();

        // ---- readback: k_s = sum of 2 partials
        {
          int fo = row * 68 + d0;
          k[s] = fbuf[0][fo] + fbuf[1][fo];
        }
      } // stages

      y += hstep * (BW0 * k[0] + BW2 * k[2] + BW3 * k[3] + BW4 * k[4] + BW5 * k[5]);
    } // steps
  } // bijectors

  out[(row0 + row) * 64 + d0] = y;
}

extern "C" void kernel_launch(void* const* d_in, const int* in_sizes, int n_in,
                              void* d_out, int out_size, void* d_ws, size_t ws_size,
                              hipStream_t stream) {
  (void)in_sizes; (void)n_in; (void)out_size; (void)ws_size;
  const float* x   = (const float*)d_in[0];
  const float* W1a = (const float*)d_in[1];
  const float* b1a = (const float*)d_in[2];
  const float* W2a = (const float*)d_in[3];
  const float* b2a = (const float*)d_in[4];
  const float* W3a = (const float*)d_in[5];
  const float* b3a = (const float*)d_in[6];
  const float* W1b = (const float*)d_in[7];
  const float* b1b = (const float*)d_in[8];
  const float* W2b = (const float*)d_in[9];
  const float* b2b = (const float*)d_in[10];
  const float* W3b = (const float*)d_in[11];
  const float* b3b = (const float*)d_in[12];
  unsigned short* ws = (unsigned short*)d_ws;
  float* out = (float*)d_out;

  hipLaunchKernelGGL(ffjord_setup, dim3(96), dim3(256), 0, stream,
                     W1a, W2a, W3a, W1b, W2b, W3b, ws);
  hipLaunchKernelGGL(ffjord_main, dim3(256), dim3(1024), 0, stream,
                     x, out, ws, W1a, b1a, b2a, b3a, W1b, b1b, b2b, b3b);
}

// Round 6
// 329.650 us; speedup vs baseline: 1.0319x; 1.0319x over previous
//
#include <hip/hip_runtime.h>

typedef __attribute__((ext_vector_type(8))) short short8;
typedef __attribute__((ext_vector_type(4))) float f32x4;

#define NSTEPS 16

__device__ __forceinline__ unsigned short bf16rne(float f) {
  unsigned int u = __float_as_uint(f);
  u += 0x7FFFu + ((u >> 16) & 1u);
  return (unsigned short)(u >> 16);
}

#if __has_builtin(__builtin_amdgcn_cvt_pk_bf16_f32)
typedef __attribute__((ext_vector_type(2))) __bf16 v2bf16;
__device__ __forceinline__ unsigned int pk2(float a, float b) {
  v2bf16 t = __builtin_amdgcn_cvt_pk_bf16_f32(a, b);
  unsigned int r;
  __builtin_memcpy(&r, &t, 4);
  return r;
}
#else
__device__ __forceinline__ unsigned int pk2(float a, float b) {
  unsigned int ua = __float_as_uint(a), ub = __float_as_uint(b);
  ua += 0x7FFFu + ((ua >> 16) & 1u);
  ub += 0x7FFFu + ((ub >> 16) & 1u);
  return (ua >> 16) | (ub & 0xFFFF0000u);
}
#endif

__device__ __forceinline__ float tanh_fast(float x) {
  // tanh(x) = 1 - 2/(e^{2x}+1); e->inf => 1, e->0 => -1 (no clamp needed)
  float e = __builtin_amdgcn_exp2f(x * 2.8853900817779268f);
  return __builtin_fmaf(-2.0f, __builtin_amdgcn_rcpf(e + 1.0f), 1.0f);
}

// Pre-shuffle fp32 weights -> bf16 MFMA fragments (B-frag of W == A-frag of W^T).
// lane holds W[k = 32*ks + 8*(lane>>4) + j][c = 16*t + (lane&15)], j=0..7
__global__ void ffjord_setup(const float* __restrict__ W1a, const float* __restrict__ W2a,
                             const float* __restrict__ W3a, const float* __restrict__ W1b,
                             const float* __restrict__ W2b, const float* __restrict__ W3b,
                             unsigned short* __restrict__ ws) {
  int gid = blockIdx.x * blockDim.x + threadIdx.x;   // 0..24575
  int bij = gid / 12288;
  int r = gid - bij * 12288;
  const float* W1 = bij ? W1b : W1a;
  const float* W2 = bij ? W2b : W2a;
  const float* W3 = bij ? W3b : W3a;
  unsigned short* o = ws + bij * 98304;
  const float* src;
  int kstride;
  if (r < 2048) {                 // W1f
    int lane = r & 63, nt = (r >> 6) & 15, ks = r >> 10;
    int k0 = ks * 32 + (lane >> 4) * 8, n = nt * 16 + (lane & 15);
    src = W1 + k0 * 256 + n; kstride = 256; o += r * 8;
  } else if (r < 10240) {         // W2f
    int rr = r - 2048;
    int lane = rr & 63, nt = (rr >> 6) & 15, ks = rr >> 10;
    int k0 = ks * 32 + (lane >> 4) * 8, n = nt * 16 + (lane & 15);
    src = W2 + k0 * 256 + n; kstride = 256; o += 16384 + rr * 8;
  } else {                        // W3f
    int rr = r - 10240;
    int lane = rr & 63, nt = (rr >> 6) & 3, ks = rr >> 8;
    int k0 = ks * 32 + (lane >> 4) * 8, n = nt * 16 + (lane & 15);
    src = W3 + k0 * 64 + n; kstride = 64; o += 81920 + rr * 8;
  }
  #pragma unroll
  for (int j = 0; j < 8; j++) o[j] = bf16rne(src[j * kstride]);
}

// 1024 threads / 16 waves, 16 batch rows per block. Wave w = m-tile w of L1/L2
// (W1/W2 frags in registers). L3 on waves 0-3 (full K=256, W3 frags from LDS);
// those waves keep k_0..k_5 and a private y-slice in registers and emit the
// NEXT stage input z_{s+1} directly as bf16 A-frags -> 3 barriers/stage, no
// fp32 readback buffer, no state threads.
__global__ __launch_bounds__(1024, 4) void ffjord_main(
    const float* __restrict__ x, float* __restrict__ out,
    const unsigned short* __restrict__ ws,
    const float* __restrict__ W1a, const float* __restrict__ b1a,
    const float* __restrict__ b2a, const float* __restrict__ b3a,
    const float* __restrict__ W1b, const float* __restrict__ b1b,
    const float* __restrict__ b2b, const float* __restrict__ b3b) {
  // zA: 8 groups of (16 rows x 8 j) ushorts, each group padded 256B->272B
  __shared__ __align__(16) unsigned short zA[1088];
  __shared__ __align__(16) unsigned short h1A[4096];   // [g8][row16][j8]
  __shared__ __align__(16) unsigned short h2A[4096];
  __shared__ __align__(16) unsigned short w3s[16384];  // W3 frags (32 KB)

  const int tid = threadIdx.x;
  const int wave = tid >> 6;        // 0..15
  const int lane = tid & 63;
  const int cl = lane & 15;
  const int qd = lane >> 4;
  const int row0 = blockIdx.x * 16;

  // L1/L2 output tile: wave w owns hidden dims [w*16, w*16+16)
  const int c0 = wave * 16 + qd * 4;
  const int hoff = (c0 >> 5) * 512 + ((c0 & 31) >> 3) * 128 + cl * 8 + (c0 & 7);
  // z A-frag read base (ks via +544 ushorts)
  const int zrb = qd * 136 + cl * 8;
  // L3 thread coords (waves 0-3): dims dl3..dl3+3 of batch row cl
  const int w3i = wave & 3;
  const int dl3 = w3i * 16 + qd * 4;
  // z-frag write slot for those 4 dims (b64-aligned)
  const int zw = (2 * w3i + (qd >> 1)) * 136 + cl * 8 + 4 * (qd & 1);

  const float hstep = 1.0f / 16.0f;

  float kreg[6][4];   // live only on waves 0-3
  f32x4 yc;           // private y slice (4 dims x 1 row), waves 0-3

  // A2[s] = DOPRI a_{s+1,j} coefficients (z for stage s+1 built at stage s)
  const float A2[5][5] = {
      {1.f / 5.f, 0.f, 0.f, 0.f, 0.f},
      {3.f / 40.f, 9.f / 40.f, 0.f, 0.f, 0.f},
      {44.f / 45.f, -56.f / 15.f, 32.f / 9.f, 0.f, 0.f},
      {19372.f / 6561.f, -25360.f / 2187.f, 64448.f / 6561.f, -212.f / 729.f, 0.f},
      {9017.f / 3168.f, -355.f / 33.f, 46732.f / 5247.f, 49.f / 176.f, -5103.f / 18656.f}};
  const float CT[6] = {0.0f, 0.2f, 0.3f, 0.8f, 8.0f / 9.0f, 1.0f};
  const float BW0 = 35.f / 384.f, BW2 = 500.f / 1113.f, BW3 = 125.f / 192.f,
              BW4 = -2187.f / 6784.f, BW5 = 11.f / 84.f;

  for (int bij = 0; bij < 2; bij++) {
    const unsigned short* wsb = ws + bij * 98304;
    const float* W1 = bij ? W1b : W1a;
    const float* b1 = bij ? b1b : b1a;
    const float* b2 = bij ? b2b : b2a;
    const float* b3 = bij ? b3b : b3a;

    f32x4 b1c = *(const f32x4*)(b1 + c0);
    f32x4 w1t4 = *(const f32x4*)(W1 + 64 * 256 + c0);
    f32x4 b2c = *(const f32x4*)(b2 + c0);
    f32x4 b3c = *(const f32x4*)(b3 + dl3);

    // register-resident W1/W2 fragments (A-operand of W^T)
    const short8* w1p = (const short8*)wsb;
    const short8* w2p = (const short8*)(wsb + 16384);
    short8 w1f[2];
    #pragma unroll
    for (int ks = 0; ks < 2; ks++)
      w1f[ks] = w1p[(ks * 16 + wave) * 64 + lane];
    short8 w2f[8];
    #pragma unroll
    for (int ks = 0; ks < 8; ks++)
      w2f[ks] = w2p[(ks * 16 + wave) * 64 + lane];

    // W3 fragments -> LDS (same layout as ws)
    {
      const uint4* s4 = (const uint4*)(wsb + 81920);
      uint4* d4 = (uint4*)w3s;
      d4[tid] = s4[tid];
      d4[tid + 1024] = s4[tid + 1024];
    }

    if (bij == 0 && wave < 4) {
      // init private y slice from x and publish z_0 = y as bf16 A-frags
      yc = *(const f32x4*)(x + (row0 + cl) * 64 + dl3);
      uint2 pv;
      pv.x = pk2(yc[0], yc[1]);
      pv.y = pk2(yc[2], yc[3]);
      *(uint2*)(zA + zw) = pv;
    }
    // bij 1: y-frag was already published by the last stage-5 L3 below
    __syncthreads();

    for (int step = 0; step < NSTEPS; step++) {
      float stepf = (float)step;
      #pragma unroll
      for (int s = 0; s < 6; s++) {
        float ts = (stepf + CT[s]) * hstep;

        // ---- layer 1: h1 = tanh(W1^T z_s + b1 + t*W1t), K=64
        {
          short8 a0 = *(const short8*)(zA + zrb);
          short8 a1 = *(const short8*)(zA + zrb + 544);
          f32x4 acc;
          #pragma unroll
          for (int r = 0; r < 4; r++)
            acc[r] = __builtin_fmaf(ts, w1t4[r], b1c[r]);
          acc = __builtin_amdgcn_mfma_f32_16x16x32_bf16(w1f[0], a0, acc, 0, 0, 0);
          acc = __builtin_amdgcn_mfma_f32_16x16x32_bf16(w1f[1], a1, acc, 0, 0, 0);
          uint2 pv;
          pv.x = pk2(tanh_fast(acc[0]), tanh_fast(acc[1]));
          pv.y = pk2(tanh_fast(acc[2]), tanh_fast(acc[3]));
          *(uint2*)(h1A + hoff) = pv;
        }
        __syncthreads();

        // ---- layer 2: h2 = tanh(W2^T h1 + b2), K=256, 2 chains of 4
        {
          f32x4 accA = b2c;
          f32x4 accB; accB[0] = 0.f; accB[1] = 0.f; accB[2] = 0.f; accB[3] = 0.f;
          #pragma unroll
          for (int ks = 0; ks < 4; ks++) {
            short8 hb = ((const short8*)h1A)[ks * 64 + lane];
            accA = __builtin_amdgcn_mfma_f32_16x16x32_bf16(w2f[ks], hb, accA, 0, 0, 0);
          }
          #pragma unroll
          for (int ks = 4; ks < 8; ks++) {
            short8 hb = ((const short8*)h1A)[ks * 64 + lane];
            accB = __builtin_amdgcn_mfma_f32_16x16x32_bf16(w2f[ks], hb, accB, 0, 0, 0);
          }
          uint2 pv;
          pv.x = pk2(tanh_fast(accA[0] + accB[0]), tanh_fast(accA[1] + accB[1]));
          pv.y = pk2(tanh_fast(accA[2] + accB[2]), tanh_fast(accA[3] + accB[3]));
          *(uint2*)(h2A + hoff) = pv;
        }
        __syncthreads();

        // ---- layer 3 + RK bookkeeping, waves 0-3 only:
        // k_s = W3^T h2 + b3 (full K=256), then emit z_{s+1} (or update y)
        // directly as bf16 A-frags from registers.
        if (wave < 4) {
          f32x4 accP = b3c;
          f32x4 accQ; accQ[0] = 0.f; accQ[1] = 0.f; accQ[2] = 0.f; accQ[3] = 0.f;
          #pragma unroll
          for (int ks = 0; ks < 8; ks += 2) {
            short8 hb0 = ((const short8*)h2A)[ks * 64 + lane];
            short8 wf0 = ((const short8*)w3s)[(ks * 4 + w3i) * 64 + lane];
            short8 hb1 = ((const short8*)h2A)[(ks + 1) * 64 + lane];
            short8 wf1 = ((const short8*)w3s)[((ks + 1) * 4 + w3i) * 64 + lane];
            accP = __builtin_amdgcn_mfma_f32_16x16x32_bf16(wf0, hb0, accP, 0, 0, 0);
            accQ = __builtin_amdgcn_mfma_f32_16x16x32_bf16(wf1, hb1, accQ, 0, 0, 0);
          }
          #pragma unroll
          for (int r = 0; r < 4; r++) kreg[s][r] = accP[r] + accQ[r];

          f32x4 z;
          if (s < 5) {
            #pragma unroll
            for (int r = 0; r < 4; r++) {
              float v = yc[r];
              #pragma unroll
              for (int j = 0; j < 5; j++)
                if (j <= s) v += (hstep * A2[s][j]) * kreg[j][r];
              z[r] = v;
            }
          } else {
            #pragma unroll
            for (int r = 0; r < 4; r++) {
              yc[r] += hstep * (BW0 * kreg[0][r] + BW2 * kreg[2][r] + BW3 * kreg[3][r] +
                                BW4 * kreg[4][r] + BW5 * kreg[5][r]);
              z[r] = yc[r];   // z_0 of the next step (or bijector) is y itself
            }
          }
          uint2 pv;
          pv.x = pk2(z[0], z[1]);
          pv.y = pk2(z[2], z[3]);
          *(uint2*)(zA + zw) = pv;
        }
        __syncthreads();
      } // stages
    } // steps
  } // bijectors

  if (wave < 4)
    *(f32x4*)(out + (row0 + cl) * 64 + dl3) = yc;
}

extern "C" void kernel_launch(void* const* d_in, const int* in_sizes, int n_in,
                              void* d_out, int out_size, void* d_ws, size_t ws_size,
                              hipStream_t stream) {
  (void)in_sizes; (void)n_in; (void)out_size; (void)ws_size;
  const float* x   = (const float*)d_in[0];
  const float* W1a = (const float*)d_in[1];
  const float* b1a = (const float*)d_in[2];
  const float* W2a = (const float*)d_in[3];
  const float* b2a = (const float*)d_in[4];
  const float* W3a = (const float*)d_in[5];
  const float* b3a = (const float*)d_in[6];
  const float* W1b = (const float*)d_in[7];
  const float* b1b = (const float*)d_in[8];
  const float* W2b = (const float*)d_in[9];
  const float* b2b = (const float*)d_in[10];
  const float* W3b = (const float*)d_in[11];
  const float* b3b = (const float*)d_in[12];
  unsigned short* ws = (unsigned short*)d_ws;
  float* out = (float*)d_out;

  hipLaunchKernelGGL(ffjord_setup, dim3(96), dim3(256), 0, stream,
                     W1a, W2a, W3a, W1b, W2b, W3b, ws);
  hipLaunchKernelGGL(ffjord_main, dim3(256), dim3(1024), 0, stream,
                     x, out, ws, W1a, b1a, b2a, b3a, W1b, b1b, b2b, b3b);
}